// Round 16
// baseline (152.012 us; speedup 1.0000x reference)
//
#include <hip/hip_runtime.h>
#include <math.h>

// B=16, LQ=LKV=2048, D=H=512, fp32 in/out. No softmax -> reassociate:
//   G_b = X_b^T X_b  [512,512] (K=2048); P = scale*Wq^T Wk
//   T2_b = Wv G_b ; Ft_b = T2_b P^T (= F^T); ctx = q F + 1 f0^T
// r16 = r15 + G-launch absorbs q-convert/weights/flag as LDS-FREE fillers
// (r14 failed because fillers' fp32 tile pushed LDS to 82KB -> 1 block/CU;
// here fillers reuse the GEMM's As scratch, kernel stays 80KB -> 2/CU), with
// G cells at stride-3 flat ids (spread over all XCDs). P moved to T2 launch's
// sec slot (WqT/WkT produced in the G launch -> consumed next launch).
// GEMM core: r15-proven <NBUF=5,DEPTH=4> counted-vmcnt global_load_lds.

typedef unsigned short u16;
typedef __attribute__((ext_vector_type(8))) short bf16x8;
typedef __attribute__((ext_vector_type(4))) float f32x4;

__device__ __forceinline__ u16 f2bf(float f) {
    union { float f; unsigned u; } a; a.f = f;
    unsigned r = a.u + 0x7FFFu + ((a.u >> 16) & 1u);
    return (u16)(r >> 16);
}
__device__ __forceinline__ float bf2f(u16 h) {
    union { unsigned u; float f; } a; a.u = ((unsigned)h) << 16;
    return a.f;
}

#define WAITV(n) asm volatile("s_waitcnt vmcnt(" #n ")" ::: "memory")

__device__ __forceinline__ void cvt16(const float4* __restrict__ iv,
                                      u16* __restrict__ ov) {
    float4 v0 = iv[0], v1 = iv[1], v2 = iv[2], v3 = iv[3];
    union { u16 h[16]; uint4 u[2]; } r;
    r.h[0] = f2bf(v0.x); r.h[1] = f2bf(v0.y); r.h[2]  = f2bf(v0.z); r.h[3]  = f2bf(v0.w);
    r.h[4] = f2bf(v1.x); r.h[5] = f2bf(v1.y); r.h[6]  = f2bf(v1.z); r.h[7]  = f2bf(v1.w);
    r.h[8] = f2bf(v2.x); r.h[9] = f2bf(v2.y); r.h[10] = f2bf(v2.z); r.h[11] = f2bf(v2.w);
    r.h[12]= f2bf(v3.x); r.h[13]= f2bf(v3.y); r.h[14] = f2bf(v3.z); r.h[15] = f2bf(v3.w);
    ((uint4*)ov)[0] = r.u[0];
    ((uint4*)ov)[1] = r.u[1];
}

// ---------------- generic MFMA GEMM (r15 core; NBUF/DEPTH templated) --------
template<bool OUT_BF16, int NBUF, int DEPTH>
__global__ __launch_bounds__(256) void gemm_k(
    const u16* __restrict__ A, const u16* __restrict__ B, void* __restrict__ Cv,
    int N, int K, long lda, int tiledA, int tiledB,
    long sA_b, long sB_b, long sC_b,
    float alpha, const float* __restrict__ rowbias, long sRB_b,
    int nb,
    const u16* __restrict__ A2, const u16* __restrict__ B2, void* __restrict__ C2,
    int N2, int K2, long lda2, float alpha2)
{
    __shared__ u16 As[NBUF][4096];
    __shared__ u16 Bs[NBUF][4096];

    const int gx = gridDim.x, gy = gridDim.y;
    const int nwg = gx * gy * (int)gridDim.z;
    const int flat = blockIdx.x + gx * (blockIdx.y + gy * blockIdx.z);
    const int nf = (flat & 7) * (nwg >> 3) + (flat >> 3);
    const int jb = nf % gx;
    const int t1 = nf / gx;
    const int ib = t1 % gy;
    const int b  = t1 / gy;
    const int i0 = ib * 128, j0 = jb * 128;

    const bool sec = (b >= nb);
    const u16* Ab  = sec ? A2 : A + (long)b * sA_b;
    const u16* Bb  = sec ? B2 : B + (long)b * sB_b;
    const int  Kl  = sec ? K2 : K;
    const long ldal= sec ? lda2 : lda;
    const float al = sec ? alpha2 : alpha;
    const int  Nl  = sec ? N2 : N;
    const bool tA  = sec ? false : (tiledA != 0);
    const bool tB  = sec ? false : (tiledB != 0);

    const int t = threadIdx.x, wv = t >> 6, ln = t & 63;
    const int lr = ln & 15, lkb = ((ln >> 4) * 8) * 2;
    const int wrow = (wv >> 1) * 64, wcol = (wv & 1) * 64;

    f32x4 acc[4][4];
#pragma unroll
    for (int m = 0; m < 4; ++m)
#pragma unroll
        for (int n = 0; n < 4; ++n) acc[m][n] = (f32x4){0.f, 0.f, 0.f, 0.f};

    const int nt = Kl >> 5;

    auto stage = [&](int buf, int k0) {
#pragma unroll
        for (int e = 0; e < 2; ++e) {
            const int o = e * 4096 + wv * 1024 + ln * 16;
            const int row = o >> 6;
            const int sw = (o & 63) ^ (((row >> 1) & 3) << 4);
            long sa, sb;
            if (tA) sa = ((long)((i0 >> 7) * nt + (k0 >> 5))) * 4096
                         + row * 32 + (sw >> 1);
            else    sa = (long)(i0 + row) * ldal + k0 + (sw >> 1);
            if (tB) sb = ((long)((j0 >> 7) * nt + (k0 >> 5))) * 4096
                         + row * 32 + (sw >> 1);
            else    sb = (long)(j0 + row) * ldal + k0 + (sw >> 1);
            __builtin_amdgcn_global_load_lds(
                (const __attribute__((address_space(1))) unsigned*)(Ab + sa),
                (__attribute__((address_space(3))) unsigned*)&As[buf][e * 2048 + wv * 512],
                16, 0, 0);
            __builtin_amdgcn_global_load_lds(
                (const __attribute__((address_space(1))) unsigned*)(Bb + sb),
                (__attribute__((address_space(3))) unsigned*)&Bs[buf][e * 2048 + wv * 512],
                16, 0, 0);
        }
    };
    auto ldfrag = [&](int c, bf16x8 (&af)[4], bf16x8 (&bfr)[4]) {
#pragma unroll
        for (int m = 0; m < 4; ++m) {
            const int row = wrow + m * 16 + lr;
            af[m] = *(const bf16x8*)
                &As[c][row * 32 + ((lkb ^ (((row >> 1) & 3) << 4)) >> 1)];
        }
#pragma unroll
        for (int n = 0; n < 4; ++n) {
            const int row = wcol + n * 16 + lr;
            bfr[n] = *(const bf16x8*)
                &Bs[c][row * 32 + ((lkb ^ (((row >> 1) & 3) << 4)) >> 1)];
        }
    };

#pragma unroll
    for (int d = 0; d < DEPTH; ++d)
        if (d < nt) stage(d, d * 32);
    {
        const int ahead = (nt < DEPTH ? nt : DEPTH) - 1;
        if      (ahead >= 3) WAITV(12);
        else if (ahead == 2) WAITV(8);
        else if (ahead == 1) WAITV(4);
        else                 WAITV(0);
    }
    __builtin_amdgcn_s_barrier();
    int c = 0;
    for (int it = 0; it < nt; ++it) {
        const int nb_ = c + DEPTH >= NBUF ? c + DEPTH - NBUF : c + DEPTH;
        if (it + DEPTH < nt) stage(nb_, (it + DEPTH) * 32);
        bf16x8 af[4], bfr[4];
        ldfrag(c, af, bfr);
        __builtin_amdgcn_s_setprio(1);
#pragma unroll
        for (int m = 0; m < 4; ++m)
#pragma unroll
            for (int n = 0; n < 4; ++n)
                acc[m][n] = __builtin_amdgcn_mfma_f32_16x16x32_bf16(
                    af[m], bfr[n], acc[m][n], 0, 0, 0);
        __builtin_amdgcn_s_setprio(0);
        {
            int ahead = nt - 2 - it;
            if (ahead > DEPTH - 1) ahead = DEPTH - 1;
            if      (ahead >= 3) WAITV(12);
            else if (ahead == 2) WAITV(8);
            else if (ahead == 1) WAITV(4);
            else                 WAITV(0);
        }
        __builtin_amdgcn_s_barrier();
        c = c + 1 >= NBUF ? 0 : c + 1;
    }

    const int rbase = (ln >> 4) * 4;
    if (OUT_BF16) {
        u16* C = sec ? (u16*)C2 : (u16*)Cv + (long)b * sC_b;
#pragma unroll
        for (int m = 0; m < 4; ++m)
#pragma unroll
            for (int n = 0; n < 4; ++n) {
                const int col = j0 + wcol + n * 16 + lr;
#pragma unroll
                for (int r = 0; r < 4; ++r) {
                    const int rowi = i0 + wrow + m * 16 + rbase + r;
                    C[(long)rowi * Nl + col] = f2bf(acc[m][n][r] * al);
                }
            }
    } else {
        float* C = (float*)Cv + (long)b * sC_b;
#pragma unroll
        for (int m = 0; m < 4; ++m)
#pragma unroll
            for (int n = 0; n < 4; ++n) {
                const int col = j0 + wcol + n * 16 + lr;
                const float bias = rowbias ? rowbias[(long)b * sRB_b + col] : 0.0f;
#pragma unroll
                for (int r = 0; r < 4; ++r) {
                    const int rowi = i0 + wrow + m * 16 + rbase + r;
                    C[(long)rowi * Nl + col] = acc[m][n][r] * al + bias;
                }
            }
    }
}

// ------------- mega G launch: G GEMM (stride-3 flat ids) + LDS-free fillers -
// flat f (grid 1536, %8==0): f%3==0, f/3<256  -> G cell (tiled Xt, K=2048)
//                            f%3==0, f/3>=256 -> weights/flag (idx2=f/3-256)
//                            f%3!=0           -> q piece ((f/3)*2 + f%3-1)
__global__ __launch_bounds__(256) void gemm_gfill(
    const u16* __restrict__ Xt, u16* __restrict__ G,
    const float* __restrict__ q, u16* __restrict__ qbf,
    const float* __restrict__ Wq, const float* __restrict__ Wk,
    const float* __restrict__ Wv,
    u16* __restrict__ WqT, u16* __restrict__ WkT, u16* __restrict__ Wvb,
    const float* __restrict__ bq, const float* __restrict__ bk,
    const float* __restrict__ bv,
    float* __restrict__ flag, float* __restrict__ f0)
{
    constexpr int NBUF = 5, DEPTH = 4;
    __shared__ u16 As[NBUF][4096];
    __shared__ u16 Bs[NBUF][4096];

    const int f = blockIdx.x;
    const int t = threadIdx.x;

    if (f % 3 != 0) {            // ---------------- q -> bf16 (16384 floats) --
        const int piece = (f / 3) * 2 + (f % 3) - 1;       // 0..1023
        const long pbase = (long)piece * 16384;
#pragma unroll
        for (int itq = 0; itq < 4; ++itq) {
            const long base = pbase + itq * 4096 + t * 16;
            cvt16((const float4*)(q + base), qbf + base);
        }
        return;
    }
    const int idx = f / 3;
    if (idx >= 256) {            // ---------------- weights / flag ------------
        const int idx2 = idx - 256;
        if (idx2 < 128) {        // WqT / WkT transpose tiles (reuse As scratch)
            float (*tile)[65] = (float(*)[65])&As[0][0];
            const float* ib = idx2 < 64 ? Wq : Wk;
            u16* ob = idx2 < 64 ? WqT : WkT;
            const int w6 = idx2 & 63;
            const int r0 = (w6 >> 3) * 64, c0 = (w6 & 7) * 64;
            const int lrow = t >> 4, lc4 = (t & 15) * 4;
#pragma unroll
            for (int i = 0; i < 4; ++i) {
                const int row = lrow + 16 * i;
                float4 v = *(const float4*)(ib + (long)(r0 + row) * 512 + c0 + lc4);
                tile[row][lc4 + 0] = v.x; tile[row][lc4 + 1] = v.y;
                tile[row][lc4 + 2] = v.z; tile[row][lc4 + 3] = v.w;
            }
            __syncthreads();
            const int oc = t & 63, og = t >> 6;
#pragma unroll
            for (int s = 0; s < 2; ++s) {
                const int rb = og * 16 + s * 8;
                union { u16 h[8]; bf16x8 v; } r;
#pragma unroll
                for (int j = 0; j < 8; ++j) r.h[j] = f2bf(tile[rb + j][oc]);
                *(bf16x8*)(ob + (long)(c0 + oc) * 512 + r0 + rb) = r.v;
            }
            return;
        }
        if (idx2 < 192) {        // Wv flat convert (4096 floats/block)
            const long base = (long)(idx2 - 128) * 4096 + t * 16;
            cvt16((const float4*)(Wv + base), Wvb + base);
            return;
        }
        if (idx2 == 192) {       // flag + f0 zero
            float* red = (float*)&As[0][0];
            float m = 0.f;
#pragma unroll
            for (int i = 0; i < 2; ++i) {
                const int e = t + 256 * i;
                m = fmaxf(m, fabsf(bq[e]));
                m = fmaxf(m, fabsf(bk[e]));
                m = fmaxf(m, fabsf(bv[e]));
            }
#pragma unroll
            for (int s = 1; s < 64; s <<= 1) m = fmaxf(m, __shfl_xor(m, s, 64));
            if ((t & 63) == 0) red[t >> 6] = m;
            __syncthreads();
            if (t == 0)
                flag[0] = fmaxf(fmaxf(red[0], red[1]), fmaxf(red[2], red[3]));
#pragma unroll
            for (int i = 0; i < 32; ++i) f0[t + 256 * i] = 0.f;
        }
        return;
    }

    // ---------------- G GEMM cell: idx in 0..255 ----------------------------
    const int b = idx >> 4, cell = idx & 15;
    const int i0 = (cell >> 2) * 128, j0 = (cell & 3) * 128;
    const u16* Ab = Xt + (long)b * (512L * 2048);
    const int nt = 64;                                     // K=2048

    const int wv = t >> 6, ln = t & 63;
    const int lr = ln & 15, lkb = ((ln >> 4) * 8) * 2;
    const int wrow = (wv >> 1) * 64, wcol = (wv & 1) * 64;

    f32x4 acc[4][4];
#pragma unroll
    for (int m = 0; m < 4; ++m)
#pragma unroll
        for (int n = 0; n < 4; ++n) acc[m][n] = (f32x4){0.f, 0.f, 0.f, 0.f};

    auto stage = [&](int buf, int k0) {
#pragma unroll
        for (int e = 0; e < 2; ++e) {
            const int o = e * 4096 + wv * 1024 + ln * 16;
            const int row = o >> 6;
            const int sw = (o & 63) ^ (((row >> 1) & 3) << 4);
            const long sa = ((long)((i0 >> 7) * nt + (k0 >> 5))) * 4096
                            + row * 32 + (sw >> 1);
            const long sb = ((long)((j0 >> 7) * nt + (k0 >> 5))) * 4096
                            + row * 32 + (sw >> 1);
            __builtin_amdgcn_global_load_lds(
                (const __attribute__((address_space(1))) unsigned*)(Ab + sa),
                (__attribute__((address_space(3))) unsigned*)&As[buf][e * 2048 + wv * 512],
                16, 0, 0);
            __builtin_amdgcn_global_load_lds(
                (const __attribute__((address_space(1))) unsigned*)(Ab + sb),
                (__attribute__((address_space(3))) unsigned*)&Bs[buf][e * 2048 + wv * 512],
                16, 0, 0);
        }
    };
    auto ldfrag = [&](int c, bf16x8 (&af)[4], bf16x8 (&bfr)[4]) {
#pragma unroll
        for (int m = 0; m < 4; ++m) {
            const int row = wrow + m * 16 + lr;
            af[m] = *(const bf16x8*)
                &As[c][row * 32 + ((lkb ^ (((row >> 1) & 3) << 4)) >> 1)];
        }
#pragma unroll
        for (int n = 0; n < 4; ++n) {
            const int row = wcol + n * 16 + lr;
            bfr[n] = *(const bf16x8*)
                &Bs[c][row * 32 + ((lkb ^ (((row >> 1) & 3) << 4)) >> 1)];
        }
    };

#pragma unroll
    for (int d = 0; d < DEPTH; ++d) stage(d, d * 32);
    WAITV(12);
    __builtin_amdgcn_s_barrier();
    int c = 0;
    for (int it = 0; it < nt; ++it) {
        const int nb_ = c + DEPTH >= NBUF ? c + DEPTH - NBUF : c + DEPTH;
        if (it + DEPTH < nt) stage(nb_, (it + DEPTH) * 32);
        bf16x8 af[4], bfr[4];
        ldfrag(c, af, bfr);
        __builtin_amdgcn_s_setprio(1);
#pragma unroll
        for (int m = 0; m < 4; ++m)
#pragma unroll
            for (int n = 0; n < 4; ++n)
                acc[m][n] = __builtin_amdgcn_mfma_f32_16x16x32_bf16(
                    af[m], bfr[n], acc[m][n], 0, 0, 0);
        __builtin_amdgcn_s_setprio(0);
        {
            int ahead = nt - 2 - it;
            if (ahead > DEPTH - 1) ahead = DEPTH - 1;
            if      (ahead >= 3) WAITV(12);
            else if (ahead == 2) WAITV(8);
            else if (ahead == 1) WAITV(4);
            else                 WAITV(0);
        }
        __builtin_amdgcn_s_barrier();
        c = c + 1 >= NBUF ? 0 : c + 1;
    }

    const int rbase = (ln >> 4) * 4;
    u16* C = G + (long)b * (512L * 512);
#pragma unroll
    for (int m = 0; m < 4; ++m)
#pragma unroll
        for (int n = 0; n < 4; ++n) {
            const int col = j0 + wcol + n * 16 + lr;
#pragma unroll
            for (int r = 0; r < 4; ++r) {
                const int rowi = i0 + wrow + m * 16 + rbase + r;
                C[(long)rowi * 512 + col] = f2bf(acc[m][n][r]);
            }
        }
}

// ---------------- prep_x: x -> TILED Xt + colsum partials -------------------
__global__ __launch_bounds__(256) void prep_x(
    const float* __restrict__ x, u16* __restrict__ Xt, float* __restrict__ partials)
{
    __shared__ float tile[64][65];
    __shared__ float cp[16][64];
    const int R = 2048, C = 512;
    const int b = blockIdx.z, t = threadIdx.x;
    const int bx = blockIdx.x, by = blockIdx.y;
    const int r0 = by * 64, c0 = bx * 64;
    const float* ib = x + (long)b * R * C;

    const int lrow = t >> 4, lc4 = (t & 15) * 4;
    float pc0 = 0.f, pc1 = 0.f, pc2 = 0.f, pc3 = 0.f;
#pragma unroll
    for (int i = 0; i < 4; ++i) {
        const int row = lrow + 16 * i;
        float4 v = *(const float4*)(ib + (long)(r0 + row) * C + c0 + lc4);
        tile[row][lc4 + 0] = v.x; tile[row][lc4 + 1] = v.y;
        tile[row][lc4 + 2] = v.z; tile[row][lc4 + 3] = v.w;
        pc0 += v.x; pc1 += v.y; pc2 += v.z; pc3 += v.w;
    }
    cp[lrow][lc4 + 0] = pc0; cp[lrow][lc4 + 1] = pc1;
    cp[lrow][lc4 + 2] = pc2; cp[lrow][lc4 + 3] = pc3;
    __syncthreads();

    const int rgn = t >> 7, cch = t & 127;
    const int d_off = cch >> 1, lh = cch & 1;
    const int dt = bx >> 1, dlb = (bx & 1) * 64;
    const int lt = 2 * by + rgn;
    u16* ob = Xt + (long)b * (512L * 2048)
              + ((long)(dt * 64 + lt)) * 4096 + (dlb + d_off) * 32 + lh * 16;
    union { u16 h[16]; uint4 u[2]; } r;
#pragma unroll
    for (int j = 0; j < 16; ++j)
        r.h[j] = f2bf(tile[rgn * 32 + lh * 16 + j][d_off]);
    ((uint4*)ob)[0] = r.u[0];
    ((uint4*)ob)[1] = r.u[1];

    if (t < 64) {
        float acc = 0.f;
#pragma unroll
        for (int i = 0; i < 16; ++i) acc += cp[i][t];
        partials[((long)b * 32 + by) * 512 + c0 + t] = acc;
    }
}

// ---------------- merged bias chain (exact; early-exit when flag==0) --------
__global__ __launch_bounds__(512) void bias_all(
    const float* __restrict__ flag, const float* __restrict__ partials,
    const float* __restrict__ Wq, const float* __restrict__ Wk, const float* __restrict__ Wv,
    const float* __restrict__ bq, const float* __restrict__ bk, const float* __restrict__ bv,
    const u16* __restrict__ G,
    float* __restrict__ w_out, float* __restrict__ vqu, float* __restrict__ vqk,
    float* __restrict__ f0, float scale, float Lf)
{
    if (flag[0] == 0.0f) return;
    __shared__ float s_sh[512], a_sh[512], u_sh[512], b_sh[512], w_sh[512];
    int b = blockIdx.x, t = threadIdx.x;
    int wv_ = t >> 6, ln = t & 63;
    float acc = 0.f;
    for (int j = 0; j < 32; ++j) acc += partials[((long)b * 32 + j) * 512 + t];
    s_sh[t] = acc;
    float pa = 0.f, pv = 0.f;
    for (int h = 0; h < 512; ++h) {
        pa += bq[h] * Wk[(long)h * 512 + t];
        pv += Wq[(long)h * 512 + t] * bk[h];
    }
    a_sh[t] = pa;
    if (b == 0) vqk[t] = pv;
    __syncthreads();
    for (int hh = 0; hh < 64; ++hh) {
        int h = wv_ * 64 + hh;
        float pu = 0.f, pw = 0.f;
#pragma unroll
        for (int c = 0; c < 8; ++c) {
            float sv = s_sh[ln + 64 * c];
            pu += Wk[(long)h * 512 + ln + 64 * c] * sv;
            pw += Wv[(long)h * 512 + ln + 64 * c] * sv;
        }
#pragma unroll
        for (int m = 1; m < 64; m <<= 1) { pu += __shfl_xor(pu, m, 64); pw += __shfl_xor(pw, m, 64); }
        if (ln == 0) { u_sh[h] = pu; w_sh[h] = pw; }
    }
    __syncthreads();
    w_out[(long)b * 512 + t] = w_sh[t];
    float bb = 0.f;
    for (int j = 0; j < 512; ++j) bb += a_sh[j] * bf2f(G[(long)b * 262144 + (long)j * 512 + t]);
    b_sh[t] = bb;
    float pvq = 0.f, d1 = 0.f, d2 = 0.f;
    for (int h = 0; h < 512; ++h) {
        pvq += Wq[(long)h * 512 + t] * u_sh[h];
        d1 += bq[h] * u_sh[h];
        d2 += bq[h] * bk[h];
    }
    vqu[(long)b * 512 + t] = pvq;
    __syncthreads();
    for (int hh = 0; hh < 64; ++hh) {
        int hp = wv_ * 64 + hh;
        float p = 0.f;
#pragma unroll
        for (int c = 0; c < 8; ++c) p += Wv[(long)hp * 512 + ln + 64 * c] * b_sh[ln + 64 * c];
#pragma unroll
        for (int m = 1; m < 64; m <<= 1) p += __shfl_xor(p, m, 64);
        if (ln == 0)
            f0[(long)b * 512 + hp] =
                scale * (p + d1 * bv[hp] + d2 * w_sh[hp] + Lf * d2 * bv[hp]);
    }
}

__global__ void rank1F(const float* __restrict__ flag,
                       u16* __restrict__ Ft, const float* __restrict__ bv,
                       const float* __restrict__ vqu, const float* __restrict__ w,
                       const float* __restrict__ vqk, float scale, float Lf)
{
    if (flag[0] == 0.0f) return;
    int b = blockIdx.y;
    long base = (long)blockIdx.x * 256 + threadIdx.x;
    for (int e = 0; e < 16; ++e) {
        long idx = base + (long)e * 16384;
        int hp = (int)(idx >> 9), d = (int)(idx & 511);
        float add = scale * (bv[hp] * vqu[(long)b * 512 + d] + w[(long)b * 512 + hp] * vqk[d]
                             + Lf * bv[hp] * vqk[d]);
        if (add != 0.f) {
            long o = (long)b * 262144 + idx;
            Ft[o] = f2bf(bf2f(Ft[o]) + add);
        }
    }
}

// ---------------- launch --------------------------------------------------
extern "C" void kernel_launch(void* const* d_in, const int* in_sizes, int n_in,
                              void* d_out, int out_size, void* d_ws, size_t ws_size,
                              hipStream_t stream) {
    const float* q  = (const float*)d_in[0];
    const float* x  = (const float*)d_in[1];
    const float* Wq = (const float*)d_in[2];
    const float* bq = (const float*)d_in[3];
    const float* Wk = (const float*)d_in[4];
    const float* bk = (const float*)d_in[5];
    const float* Wv = (const float*)d_in[6];
    const float* bv = (const float*)d_in[7];
    float* out = (float*)d_out;

    const int Bn = 16, LQ = 2048, LKV = 2048, D = 512, H = 512;
    const float scale = 1.0f / sqrtf((float)H);

    char* p = (char*)d_ws;
    u16* Xt   = (u16*)p; p += (size_t)Bn * D * LKV * 2;   // 32MB, TILED
    u16* qbf  = (u16*)p; p += (size_t)Bn * LQ * D * 2;    // 32MB
    u16* G    = (u16*)p; p += (size_t)Bn * D * D * 2;     // 8MB; reused as Ft
    u16* T2   = (u16*)p; p += (size_t)Bn * H * D * 2;     // 8MB
    u16* P    = (u16*)p; p += (size_t)D * H * 2;
    u16* WqT  = (u16*)p; p += (size_t)D * H * 2;
    u16* WkT  = (u16*)p; p += (size_t)D * H * 2;
    u16* Wvb  = (u16*)p; p += (size_t)H * D * 2;
    float* partials = (float*)p; p += (size_t)Bn * 32 * D * 4;  // 1MB
    float* w    = (float*)p; p += (size_t)Bn * H * 4;
    float* vqu  = (float*)p; p += (size_t)Bn * D * 4;
    float* f0   = (float*)p; p += (size_t)Bn * H * 4;
    float* vqk  = (float*)p; p += (size_t)D * 4;
    float* flag = (float*)p; p += 4 * 4;
    u16* Ft = G;

    // 1) prep: x -> Xt (tiled) + colsum partials
    prep_x<<<dim3(8, 32, Bn), dim3(256), 0, stream>>>(x, Xt, partials);

    // 2) mega: G GEMM (stride-3 flat ids) + q-convert + weights + flag fillers
    gemm_gfill<<<dim3(1536), dim3(256), 0, stream>>>(
        Xt, G, q, qbf, Wq, Wk, Wv, WqT, WkT, Wvb, bq, bk, bv, flag, f0);

    // 3) merged bias chain (early-exit when flag==0)
    bias_all<<<dim3(Bn), dim3(512), 0, stream>>>(flag, partials, Wq, Wk, Wv,
                                                 bq, bk, bv, G, w, vqu, vqk, f0,
                                                 scale, (float)LKV);

    // 4) T2 = Wv G (z<16)  ∥  P = scale*WqT WkT^T (z==16, sec slot)
    gemm_k<true, 5, 4><<<dim3(4, 4, Bn + 1), dim3(256), 0, stream>>>(
        Wvb, G, T2, D, D, (long)D, 0, 0,
        0L, (long)D * D, (long)H * D, 1.0f, nullptr, 0L,
        Bn, WqT, WkT, P, D, H, (long)H, scale);

    // 5) Ft = T2 P^T  (overwrites G slot; G last read in step 4)
    gemm_k<true, 5, 4><<<dim3(4, 4, Bn), dim3(256), 0, stream>>>(
        T2, P, Ft, D, H, (long)H, 0, 0,
        (long)H * D, 0L, (long)H * D, 1.0f, nullptr, 0L,
        Bn, nullptr, nullptr, nullptr, 0, 0, 0L, 0.0f);

    // 6) rank-1 bias fixup on Ft (early-exit)
    rank1F<<<dim3(64, Bn), dim3(256), 0, stream>>>(flag, Ft, bv, vqu, w, vqk,
                                                   scale, (float)LKV);

    // 7) ctx = q F + 1 f0^T
    gemm_k<false, 5, 4><<<dim3(4, 16, Bn), dim3(256), 0, stream>>>(
        qbf, Ft, out, H, D, (long)D, 0, 0,
        (long)LQ * D, (long)H * D, (long)LQ * H, 1.0f, f0, (long)H,
        Bn, nullptr, nullptr, nullptr, 0, 0, 0L, 0.0f);
}

// Round 17
// 136.193 us; speedup vs baseline: 1.1161x; 1.1161x over previous
//
#include <hip/hip_runtime.h>
#include <math.h>

// B=16, LQ=LKV=2048, D=H=512, fp32 in/out. No softmax -> reassociate:
//   G_b = X_b^T X_b  [512,512] (K=2048); P = scale*Wq^T Wk (fused into G launch)
//   T2_b = Wv G_b ; Ft_b = T2_b P^T (= F^T); ctx = q F + 1 f0^T
// r17 = r15 minus the q round-trip: ctx GEMM stages q as FP32 via
// global_load_lds (intrinsics only -> exact counted vmcnt) and converts
// fp32->bf16 at fragment read with v_cvt_pk_bf16_f32. prep_all drops its
// q planes. Other GEMMs: r15-proven <NBUF=5,DEPTH=4> tiled/linear bf16 core.

typedef unsigned short u16;
typedef __attribute__((ext_vector_type(8))) short bf16x8;
typedef __attribute__((ext_vector_type(4))) float f32x4;

__device__ __forceinline__ u16 f2bf(float f) {
    union { float f; unsigned u; } a; a.f = f;
    unsigned r = a.u + 0x7FFFu + ((a.u >> 16) & 1u);
    return (u16)(r >> 16);
}
__device__ __forceinline__ float bf2f(u16 h) {
    union { unsigned u; float f; } a; a.u = ((unsigned)h) << 16;
    return a.f;
}

#define WAITV(n) asm volatile("s_waitcnt vmcnt(" #n ")" ::: "memory")

// ---------------- MFMA GEMM (r15 core; NBUF/DEPTH templated) ----------------
template<bool OUT_BF16, int NBUF, int DEPTH>
__global__ __launch_bounds__(256) void gemm_k(
    const u16* __restrict__ A, const u16* __restrict__ B, void* __restrict__ Cv,
    int N, int K, long lda, int tiledA, int tiledB,
    long sA_b, long sB_b, long sC_b,
    float alpha, const float* __restrict__ rowbias, long sRB_b,
    int nb,
    const u16* __restrict__ A2, const u16* __restrict__ B2, void* __restrict__ C2,
    int N2, int K2, long lda2, float alpha2)
{
    __shared__ u16 As[NBUF][4096];
    __shared__ u16 Bs[NBUF][4096];

    const int gx = gridDim.x, gy = gridDim.y;
    const int nwg = gx * gy * (int)gridDim.z;
    const int flat = blockIdx.x + gx * (blockIdx.y + gy * blockIdx.z);
    const int nf = (flat & 7) * (nwg >> 3) + (flat >> 3);
    const int jb = nf % gx;
    const int t1 = nf / gx;
    const int ib = t1 % gy;
    const int b  = t1 / gy;
    const int i0 = ib * 128, j0 = jb * 128;

    const bool sec = (b >= nb);
    const u16* Ab  = sec ? A2 : A + (long)b * sA_b;
    const u16* Bb  = sec ? B2 : B + (long)b * sB_b;
    const int  Kl  = sec ? K2 : K;
    const long ldal= sec ? lda2 : lda;
    const float al = sec ? alpha2 : alpha;
    const int  Nl  = sec ? N2 : N;
    const bool tA  = sec ? false : (tiledA != 0);
    const bool tB  = sec ? false : (tiledB != 0);

    const int t = threadIdx.x, wv = t >> 6, ln = t & 63;
    const int lr = ln & 15, lkb = ((ln >> 4) * 8) * 2;
    const int wrow = (wv >> 1) * 64, wcol = (wv & 1) * 64;

    f32x4 acc[4][4];
#pragma unroll
    for (int m = 0; m < 4; ++m)
#pragma unroll
        for (int n = 0; n < 4; ++n) acc[m][n] = (f32x4){0.f, 0.f, 0.f, 0.f};

    const int nt = Kl >> 5;

    auto stage = [&](int buf, int k0) {
#pragma unroll
        for (int e = 0; e < 2; ++e) {
            const int o = e * 4096 + wv * 1024 + ln * 16;
            const int row = o >> 6;
            const int sw = (o & 63) ^ (((row >> 1) & 3) << 4);
            long sa, sb;
            if (tA) sa = ((long)((i0 >> 7) * nt + (k0 >> 5))) * 4096
                         + row * 32 + (sw >> 1);
            else    sa = (long)(i0 + row) * ldal + k0 + (sw >> 1);
            if (tB) sb = ((long)((j0 >> 7) * nt + (k0 >> 5))) * 4096
                         + row * 32 + (sw >> 1);
            else    sb = (long)(j0 + row) * ldal + k0 + (sw >> 1);
            __builtin_amdgcn_global_load_lds(
                (const __attribute__((address_space(1))) unsigned*)(Ab + sa),
                (__attribute__((address_space(3))) unsigned*)&As[buf][e * 2048 + wv * 512],
                16, 0, 0);
            __builtin_amdgcn_global_load_lds(
                (const __attribute__((address_space(1))) unsigned*)(Bb + sb),
                (__attribute__((address_space(3))) unsigned*)&Bs[buf][e * 2048 + wv * 512],
                16, 0, 0);
        }
    };
    auto ldfrag = [&](int c, bf16x8 (&af)[4], bf16x8 (&bfr)[4]) {
#pragma unroll
        for (int m = 0; m < 4; ++m) {
            const int row = wrow + m * 16 + lr;
            af[m] = *(const bf16x8*)
                &As[c][row * 32 + ((lkb ^ (((row >> 1) & 3) << 4)) >> 1)];
        }
#pragma unroll
        for (int n = 0; n < 4; ++n) {
            const int row = wcol + n * 16 + lr;
            bfr[n] = *(const bf16x8*)
                &Bs[c][row * 32 + ((lkb ^ (((row >> 1) & 3) << 4)) >> 1)];
        }
    };

#pragma unroll
    for (int d = 0; d < DEPTH; ++d)
        if (d < nt) stage(d, d * 32);
    {
        const int ahead = (nt < DEPTH ? nt : DEPTH) - 1;
        if      (ahead >= 3) WAITV(12);
        else if (ahead == 2) WAITV(8);
        else if (ahead == 1) WAITV(4);
        else                 WAITV(0);
    }
    __builtin_amdgcn_s_barrier();
    int c = 0;
    for (int it = 0; it < nt; ++it) {
        const int nb_ = c + DEPTH >= NBUF ? c + DEPTH - NBUF : c + DEPTH;
        if (it + DEPTH < nt) stage(nb_, (it + DEPTH) * 32);
        bf16x8 af[4], bfr[4];
        ldfrag(c, af, bfr);
        __builtin_amdgcn_s_setprio(1);
#pragma unroll
        for (int m = 0; m < 4; ++m)
#pragma unroll
            for (int n = 0; n < 4; ++n)
                acc[m][n] = __builtin_amdgcn_mfma_f32_16x16x32_bf16(
                    af[m], bfr[n], acc[m][n], 0, 0, 0);
        __builtin_amdgcn_s_setprio(0);
        {
            int ahead = nt - 2 - it;
            if (ahead > DEPTH - 1) ahead = DEPTH - 1;
            if      (ahead >= 3) WAITV(12);
            else if (ahead == 2) WAITV(8);
            else if (ahead == 1) WAITV(4);
            else                 WAITV(0);
        }
        __builtin_amdgcn_s_barrier();
        c = c + 1 >= NBUF ? 0 : c + 1;
    }

    const int rbase = (ln >> 4) * 4;
    if (OUT_BF16) {
        u16* C = sec ? (u16*)C2 : (u16*)Cv + (long)b * sC_b;
#pragma unroll
        for (int m = 0; m < 4; ++m)
#pragma unroll
            for (int n = 0; n < 4; ++n) {
                const int col = j0 + wcol + n * 16 + lr;
#pragma unroll
                for (int r = 0; r < 4; ++r) {
                    const int rowi = i0 + wrow + m * 16 + rbase + r;
                    C[(long)rowi * Nl + col] = f2bf(acc[m][n][r] * al);
                }
            }
    } else {
        float* C = (float*)Cv + (long)b * sC_b;
#pragma unroll
        for (int m = 0; m < 4; ++m)
#pragma unroll
            for (int n = 0; n < 4; ++n) {
                const int col = j0 + wcol + n * 16 + lr;
                const float bias = rowbias ? rowbias[(long)b * sRB_b + col] : 0.0f;
#pragma unroll
                for (int r = 0; r < 4; ++r) {
                    const int rowi = i0 + wrow + m * 16 + rbase + r;
                    C[(long)rowi * Nl + col] = acc[m][n][r] * al + bias;
                }
            }
    }
}

// ---------------- ctx GEMM: A = q FP32 staged via global_load_lds -----------
// C[2048,512] = q[2048,512] * Ft[512,512]^T + f0 ; grid (4,16,16)
__global__ __launch_bounds__(256) void gemm_ctx(
    const float* __restrict__ A, const u16* __restrict__ B, float* __restrict__ C,
    const float* __restrict__ rowbias)
{
    constexpr int NBUF = 3, DEPTH = 2;
    __shared__ float Af[NBUF][4096];   // 16KB each (128 rows x 32 fp32)
    __shared__ u16  Bs[NBUF][4096];    // 8KB each

    const int gx = gridDim.x, gy = gridDim.y;
    const int nwg = gx * gy * (int)gridDim.z;
    const int flat = blockIdx.x + gx * (blockIdx.y + gy * blockIdx.z);
    const int nf = (flat & 7) * (nwg >> 3) + (flat >> 3);
    const int jb = nf % gx;
    const int t1 = nf / gx;
    const int ib = t1 % gy;
    const int b  = t1 / gy;
    const int i0 = ib * 128, j0 = jb * 128;
    const float* Ab = A + (long)b * (2048L * 512);
    const u16*   Bb = B + (long)b * (512L * 512);

    const int t = threadIdx.x, wv = t >> 6, ln = t & 63;
    const int lr = ln & 15, lke = (ln >> 4) * 8;        // frag k elem offset
    const int lkb = lke * 2;
    const int wrow = (wv >> 1) * 64, wcol = (wv & 1) * 64;

    f32x4 acc[4][4];
#pragma unroll
    for (int m = 0; m < 4; ++m)
#pragma unroll
        for (int n = 0; n < 4; ++n) acc[m][n] = (f32x4){0.f, 0.f, 0.f, 0.f};

    const int nt = 16;                                  // K=512

    // A stage: 16KB fp32 tile, 4 intrinsic rounds; source pre-swizzled
    // (chunk ^ (row&7)<<4 within the 128B row). B stage: proven bf16 path.
    auto stage = [&](int buf, int k0) {
#pragma unroll
        for (int e = 0; e < 4; ++e) {
            const int o = e * 4096 + wv * 1024 + ln * 16;   // byte in 16KB tile
            const int row = o >> 7;
            const int sw = (o & 127) ^ ((row & 7) << 4);
            __builtin_amdgcn_global_load_lds(
                (const __attribute__((address_space(1))) unsigned*)
                    (Ab + (long)(i0 + row) * 512 + k0 + (sw >> 2)),
                (__attribute__((address_space(3))) unsigned*)&Af[buf][e * 1024 + wv * 256],
                16, 0, 0);
        }
#pragma unroll
        for (int e = 0; e < 2; ++e) {
            const int o = e * 4096 + wv * 1024 + ln * 16;
            const int row = o >> 6;
            const int sw = (o & 63) ^ (((row >> 1) & 3) << 4);
            __builtin_amdgcn_global_lds:
            ;
        }
    };
    (void)stage;

    auto stageA = [&](int buf, int k0) {
#pragma unroll
        for (int e = 0; e < 4; ++e) {
            const int o = e * 4096 + wv * 1024 + ln * 16;
            const int row = o >> 7;
            const int sw = (o & 127) ^ ((row & 7) << 4);
            __builtin_amdgcn_global_load_lds(
                (const __attribute__((address_space(1))) unsigned*)
                    (Ab + (long)(i0 + row) * 512 + k0 + (sw >> 2)),
                (__attribute__((address_space(3))) unsigned*)&Af[buf][e * 1024 + wv * 256],
                16, 0, 0);
        }
    };
    auto stageB = [&](int buf, int k0) {
#pragma unroll
        for (int e = 0; e < 2; ++e) {
            const int o = e * 4096 + wv * 1024 + ln * 16;
            const int row = o >> 6;
            const int sw = (o & 63) ^ (((row >> 1) & 3) << 4);
            __builtin_amdgcn_global_load_lds(
                (const __attribute__((address_space(1))) unsigned*)
                    (Bb + (long)(j0 + row) * 512 + k0 + (sw >> 1)),
                (__attribute__((address_space(3))) unsigned*)&Bs[buf][e * 2048 + wv * 512],
                16, 0, 0);
        }
    };

    auto ldfrag = [&](int c, bf16x8 (&af)[4], bf16x8 (&bfr)[4]) {
        const char* pA = (const char*)&Af[c][0];
#pragma unroll
        for (int m = 0; m < 4; ++m) {
            const int row = wrow + m * 16 + lr;
            const int key = (row & 7) << 4;
            float4 lo = *(const float4*)(pA + row * 128 + ((lke * 4) ^ key));
            float4 hi = *(const float4*)(pA + row * 128 + ((lke * 4 + 16) ^ key));
            unsigned w0, w1, w2, w3;
            asm("v_cvt_pk_bf16_f32 %0, %1, %2" : "=v"(w0) : "v"(lo.x), "v"(lo.y));
            asm("v_cvt_pk_bf16_f32 %0, %1, %2" : "=v"(w1) : "v"(lo.z), "v"(lo.w));
            asm("v_cvt_pk_bf16_f32 %0, %1, %2" : "=v"(w2) : "v"(hi.x), "v"(hi.y));
            asm("v_cvt_pk_bf16_f32 %0, %1, %2" : "=v"(w3) : "v"(hi.z), "v"(hi.w));
            union { unsigned u[4]; bf16x8 v; } r;
            r.u[0] = w0; r.u[1] = w1; r.u[2] = w2; r.u[3] = w3;
            af[m] = r.v;
        }
#pragma unroll
        for (int n = 0; n < 4; ++n) {
            const int row = wcol + n * 16 + lr;
            bfr[n] = *(const bf16x8*)
                &Bs[c][row * 32 + ((lkb ^ (((row >> 1) & 3) << 4)) >> 1)];
        }
    };

    stageA(0, 0); stageB(0, 0);
    stageA(1, 32); stageB(1, 32);
    WAITV(6);                                           // tile0 (6 ops) done
    __builtin_amdgcn_s_barrier();
    int c = 0;
    for (int it = 0; it < nt; ++it) {
        const int nb_ = c + DEPTH >= NBUF ? c + DEPTH - NBUF : c + DEPTH;
        const bool pf = it + DEPTH < nt;
        if (pf) { stageA(nb_, (it + DEPTH) * 32); stageB(nb_, (it + DEPTH) * 32); }
        bf16x8 af[4], bfr[4];
        ldfrag(c, af, bfr);
        __builtin_amdgcn_s_setprio(1);
#pragma unroll
        for (int m = 0; m < 4; ++m)
#pragma unroll
            for (int n = 0; n < 4; ++n)
                acc[m][n] = __builtin_amdgcn_mfma_f32_16x16x32_bf16(
                    af[m], bfr[n], acc[m][n], 0, 0, 0);
        __builtin_amdgcn_s_setprio(0);
        if (pf) WAITV(6);                               // tile it+1 done
        else    WAITV(0);
        __builtin_amdgcn_s_barrier();
        c = c + 1 >= NBUF ? 0 : c + 1;
    }

    const int rbase = (ln >> 4) * 4;
    float* Cb = C + (long)b * (2048L * 512);
#pragma unroll
    for (int m = 0; m < 4; ++m)
#pragma unroll
        for (int n = 0; n < 4; ++n) {
            const int col = j0 + wcol + n * 16 + lr;
            const float bias = rowbias[(long)b * 512 + col];
#pragma unroll
            for (int r = 0; r < 4; ++r) {
                const int rowi = i0 + wrow + m * 16 + rbase + r;
                Cb[(long)rowi * 512 + col] = acc[m][n][r] + bias;
            }
        }
}

// ---------------- prep: z<16 x-transpose(tiled Xt)+colsum; z==16: weights+flag
__global__ __launch_bounds__(256) void prep_all(
    const float* __restrict__ x, u16* __restrict__ Xt, float* __restrict__ partials,
    const float* __restrict__ Wq, const float* __restrict__ Wk,
    const float* __restrict__ Wv,
    u16* __restrict__ WqT, u16* __restrict__ WkT, u16* __restrict__ Wvb,
    const float* __restrict__ bq, const float* __restrict__ bk,
    const float* __restrict__ bv,
    float* __restrict__ flag, float* __restrict__ f0)
{
    __shared__ float tile[64][65];
    __shared__ float cp[16][64];
    const int R = 2048, C = 512;
    const int z = blockIdx.z, t = threadIdx.x;
    const int bx = blockIdx.x, by = blockIdx.y;

    if (z == 16) {
        if (by < 24) {                       // ---- weights prep ----
            const float* ib = by < 8 ? Wq : (by < 16 ? Wk : Wv);
            u16* ob = by < 8 ? WqT : (by < 16 ? WkT : Wvb);
            const int r0 = (by & 7) * 64, c0 = bx * 64;
            if (by >= 16) {                  // Wv flat convert, 16/thread
                const long base = ((long)((by & 7) * 8 + bx) * 256 + t) * 16;
                const float4* iv = (const float4*)(ib + base);
                u16* ov = ob + base;
                float4 v0 = iv[0], v1 = iv[1], v2 = iv[2], v3 = iv[3];
                union { u16 h[16]; uint4 u[2]; } r;
                r.h[0] = f2bf(v0.x); r.h[1] = f2bf(v0.y); r.h[2]  = f2bf(v0.z); r.h[3]  = f2bf(v0.w);
                r.h[4] = f2bf(v1.x); r.h[5] = f2bf(v1.y); r.h[6]  = f2bf(v1.z); r.h[7]  = f2bf(v1.w);
                r.h[8] = f2bf(v2.x); r.h[9] = f2bf(v2.y); r.h[10] = f2bf(v2.z); r.h[11] = f2bf(v2.w);
                r.h[12]= f2bf(v3.x); r.h[13]= f2bf(v3.y); r.h[14] = f2bf(v3.z); r.h[15] = f2bf(v3.w);
                ((uint4*)ov)[0] = r.u[0];
                ((uint4*)ov)[1] = r.u[1];
                return;
            }
            const int lrow = t >> 4, lc4 = (t & 15) * 4;
#pragma unroll
            for (int i = 0; i < 4; ++i) {
                const int row = lrow + 16 * i;
                float4 v = *(const float4*)(ib + (long)(r0 + row) * 512 + c0 + lc4);
                tile[row][lc4 + 0] = v.x; tile[row][lc4 + 1] = v.y;
                tile[row][lc4 + 2] = v.z; tile[row][lc4 + 3] = v.w;
            }
            __syncthreads();
            const int oc = t & 63, og = t >> 6;
#pragma unroll
            for (int s = 0; s < 2; ++s) {
                const int rb = og * 16 + s * 8;
                union { u16 h[8]; bf16x8 v; } r;
#pragma unroll
                for (int j = 0; j < 8; ++j) r.h[j] = f2bf(tile[rb + j][oc]);
                *(bf16x8*)(ob + (long)(c0 + oc) * 512 + r0 + rb) = r.v;
            }
            return;
        }
        if (by == 24 && bx == 0) {           // ---- bias flag + f0 zero ----
            float m = 0.f;
#pragma unroll
            for (int i = 0; i < 2; ++i) {
                const int e = t + 256 * i;
                m = fmaxf(m, fabsf(bq[e]));
                m = fmaxf(m, fabsf(bk[e]));
                m = fmaxf(m, fabsf(bv[e]));
            }
#pragma unroll
            for (int s = 1; s < 64; s <<= 1) m = fmaxf(m, __shfl_xor(m, s, 64));
            if ((t & 63) == 0) cp[0][t >> 6] = m;
            __syncthreads();
            if (t == 0)
                flag[0] = fmaxf(fmaxf(cp[0][0], cp[0][1]), fmaxf(cp[0][2], cp[0][3]));
#pragma unroll
            for (int i = 0; i < 32; ++i) f0[t + 256 * i] = 0.f;
        }
        return;
    }

    // ---- x 64x64 tile -> TILED Xt [4 dt][64 lt][128][32] + colsum partials ----
    const int b = z;
    const int r0 = by * 64, c0 = bx * 64;
    const float* ib = x + (long)b * R * C;

    const int lrow = t >> 4, lc4 = (t & 15) * 4;
    float pc0 = 0.f, pc1 = 0.f, pc2 = 0.f, pc3 = 0.f;
#pragma unroll
    for (int i = 0; i < 4; ++i) {
        const int row = lrow + 16 * i;
        float4 v = *(const float4*)(ib + (long)(r0 + row) * C + c0 + lc4);
        tile[row][lc4 + 0] = v.x; tile[row][lc4 + 1] = v.y;
        tile[row][lc4 + 2] = v.z; tile[row][lc4 + 3] = v.w;
        pc0 += v.x; pc1 += v.y; pc2 += v.z; pc3 += v.w;
    }
    cp[lrow][lc4 + 0] = pc0; cp[lrow][lc4 + 1] = pc1;
    cp[lrow][lc4 + 2] = pc2; cp[lrow][lc4 + 3] = pc3;
    __syncthreads();

    const int rgn = t >> 7, cch = t & 127;
    const int d_off = cch >> 1, lh = cch & 1;
    const int dt = bx >> 1, dlb = (bx & 1) * 64;
    const int lt = 2 * by + rgn;
    u16* ob = Xt + (long)b * (512L * 2048)
              + ((long)(dt * 64 + lt)) * 4096 + (dlb + d_off) * 32 + lh * 16;
    union { u16 h[16]; uint4 u[2]; } r;
#pragma unroll
    for (int j = 0; j < 16; ++j)
        r.h[j] = f2bf(tile[rgn * 32 + lh * 16 + j][d_off]);
    ((uint4*)ob)[0] = r.u[0];
    ((uint4*)ob)[1] = r.u[1];

    if (t < 64) {
        float acc = 0.f;
#pragma unroll
        for (int i = 0; i < 16; ++i) acc += cp[i][t];
        partials[((long)b * 32 + by) * 512 + c0 + t] = acc;
    }
}

// ---------------- merged bias chain (exact; early-exit when flag==0) --------
__global__ __launch_bounds__(512) void bias_all(
    const float* __restrict__ flag, const float* __restrict__ partials,
    const float* __restrict__ Wq, const float* __restrict__ Wk, const float* __restrict__ Wv,
    const float* __restrict__ bq, const float* __restrict__ bk, const float* __restrict__ bv,
    const u16* __restrict__ G,
    float* __restrict__ w_out, float* __restrict__ vqu, float* __restrict__ vqk,
    float* __restrict__ f0, float scale, float Lf)
{
    if (flag[0] == 0.0f) return;
    __shared__ float s_sh[512], a_sh[512], u_sh[512], b_sh[512], w_sh[512];
    int b = blockIdx.x, t = threadIdx.x;
    int wv_ = t >> 6, ln = t & 63;
    float acc = 0.f;
    for (int j = 0; j < 32; ++j) acc += partials[((long)b * 32 + j) * 512 + t];
    s_sh[t] = acc;
    float pa = 0.f, pv = 0.f;
    for (int h = 0; h < 512; ++h) {
        pa += bq[h] * Wk[(long)h * 512 + t];
        pv += Wq[(long)h * 512 + t] * bk[h];
    }
    a_sh[t] = pa;
    if (b == 0) vqk[t] = pv;
    __syncthreads();
    for (int hh = 0; hh < 64; ++hh) {
        int h = wv_ * 64 + hh;
        float pu = 0.f, pw = 0.f;
#pragma unroll
        for (int c = 0; c < 8; ++c) {
            float sv = s_sh[ln + 64 * c];
            pu += Wk[(long)h * 512 + ln + 64 * c] * sv;
            pw += Wv[(long)h * 512 + ln + 64 * c] * sv;
        }
#pragma unroll
        for (int m = 1; m < 64; m <<= 1) { pu += __shfl_xor(pu, m, 64); pw += __shfl_xor(pw, m, 64); }
        if (ln == 0) { u_sh[h] = pu; w_sh[h] = pw; }
    }
    __syncthreads();
    w_out[(long)b * 512 + t] = w_sh[t];
    float bb = 0.f;
    for (int j = 0; j < 512; ++j) bb += a_sh[j] * bf2f(G[(long)b * 262144 + (long)j * 512 + t]);
    b_sh[t] = bb;
    float pvq = 0.f, d1 = 0.f, d2 = 0.f;
    for (int h = 0; h < 512; ++h) {
        pvq += Wq[(long)h * 512 + t] * u_sh[h];
        d1 += bq[h] * u_sh[h];
        d2 += bq[h] * bk[h];
    }
    vqu[(long)b * 512 + t] = pvq;
    __syncthreads();
    for (int hh = 0; hh < 64; ++hh) {
        int hp = wv_ * 64 + hh;
        float p = 0.f;
#pragma unroll
        for (int c = 0; c < 8; ++c) p += Wv[(long)hp * 512 + ln + 64 * c] * b_sh[ln + 64 * c];
#pragma unroll
        for (int m = 1; m < 64; m <<= 1) p += __shfl_xor(p, m, 64);
        if (ln == 0)
            f0[(long)b * 512 + hp] =
                scale * (p + d1 * bv[hp] + d2 * w_sh[hp] + Lf * d2 * bv[hp]);
    }
}

__global__ void rank1F(const float* __restrict__ flag,
                       u16* __restrict__ Ft, const float* __restrict__ bv,
                       const float* __restrict__ vqu, const float* __restrict__ w,
                       const float* __restrict__ vqk, float scale, float Lf)
{
    if (flag[0] == 0.0f) return;
    int b = blockIdx.y;
    long base = (long)blockIdx.x * 256 + threadIdx.x;
    for (int e = 0; e < 16; ++e) {
        long idx = base + (long)e * 16384;
        int hp = (int)(idx >> 9), d = (int)(idx & 511);
        float add = scale * (bv[hp] * vqu[(long)b * 512 + d] + w[(long)b * 512 + hp] * vqk[d]
                             + Lf * bv[hp] * vqk[d]);
        if (add != 0.f) {
            long o = (long)b * 262144 + idx;
            Ft[o] = f2bf(bf2f(Ft[o]) + add);
        }
    }
}

// ---------------- launch --------------------------------------------------
extern "C" void kernel_launch(void* const* d_in, const int* in_sizes, int n_in,
                              void* d_out, int out_size, void* d_ws, size_t ws_size,
                              hipStream_t stream) {
    const float* q  = (const float*)d_in[0];
    const float* x  = (const float*)d_in[1];
    const float* Wq = (const float*)d_in[2];
    const float* bq = (const float*)d_in[3];
    const float* Wk = (const float*)d_in[4];
    const float* bk = (const float*)d_in[5];
    const float* Wv = (const float*)d_in[6];
    const float* bv = (const float*)d_in[7];
    float* out = (float*)d_out;

    const int Bn = 16, LQ = 2048, LKV = 2048, D = 512, H = 512;
    const float scale = 1.0f / sqrtf((float)H);

    char* p = (char*)d_ws;
    u16* Xt   = (u16*)p; p += (size_t)Bn * D * LKV * 2;   // 32MB, TILED
    u16* G    = (u16*)p; p += (size_t)Bn * D * D * 2;     // 8MB; reused as Ft
    u16* T2   = (u16*)p; p += (size_t)Bn * H * D * 2;     // 8MB
    u16* P    = (u16*)p; p += (size_t)D * H * 2;
    u16* WqT  = (u16*)p; p += (size_t)D * H * 2;
    u16* WkT  = (u16*)p; p += (size_t)D * H * 2;
    u16* Wvb  = (u16*)p; p += (size_t)H * D * 2;
    float* partials = (float*)p; p += (size_t)Bn * 32 * D * 4;  // 1MB
    float* w    = (float*)p; p += (size_t)Bn * H * 4;
    float* vqu  = (float*)p; p += (size_t)Bn * D * 4;
    float* f0   = (float*)p; p += (size_t)Bn * H * 4;
    float* vqk  = (float*)p; p += (size_t)D * 4;
    float* flag = (float*)p; p += 4 * 4;
    u16* Ft = G;

    // 1) prep: x->Xt(tiled)+colsum, weights, bias flag/f0 (q untouched)
    prep_all<<<dim3(8, 32, 17), dim3(256), 0, stream>>>(
        x, Xt, partials, Wq, Wk, Wv, WqT, WkT, Wvb, bq, bk, bv, flag, f0);

    // 2) G = Xt Xt^T (tiled operands, z<16, K=2048) ∥ P (z==16, K=512)
    gemm_k<true, 5, 4><<<dim3(4, 4, Bn + 1), dim3(256), 0, stream>>>(
        Xt, Xt, G, D, LKV, (long)LKV, 1, 1,
        (long)D * LKV, (long)D * LKV, (long)D * D, 1.0f, nullptr, 0L,
        Bn, WqT, WkT, P, D, H, (long)H, scale);

    // 3) merged bias chain (early-exit when flag==0)
    bias_all<<<dim3(Bn), dim3(512), 0, stream>>>(flag, partials, Wq, Wk, Wv,
                                                 bq, bk, bv, G, w, vqu, vqk, f0,
                                                 scale, (float)LKV);

    // 4) T2 = Wv G
    gemm_k<true, 5, 4><<<dim3(4, 4, Bn), dim3(256), 0, stream>>>(
        Wvb, G, T2, D, D, (long)D, 0, 0,
        0L, (long)D * D, (long)H * D, 1.0f, nullptr, 0L,
        Bn, nullptr, nullptr, nullptr, 0, 0, 0L, 0.0f);

    // 5) Ft = T2 P^T  (overwrites G slot; G last read in step 4)
    gemm_k<true, 5, 4><<<dim3(4, 4, Bn), dim3(256), 0, stream>>>(
        T2, P, Ft, D, H, (long)H, 0, 0,
        (long)H * D, 0L, (long)H * D, 1.0f, nullptr, 0L,
        Bn, nullptr, nullptr, nullptr, 0, 0, 0L, 0.0f);

    // 6) rank-1 bias fixup on Ft (early-exit)
    rank1F<<<dim3(64, Bn), dim3(256), 0, stream>>>(flag, Ft, bv, vqu, w, vqk,
                                                   scale, (float)LKV);

    // 7) ctx = q F + 1 f0^T  (q fp32 staged to LDS, cvt at fragment read)
    gemm_ctx<<<dim3(4, 16, Bn), dim3(256), 0, stream>>>(q, Ft, out, f0);
}